// Round 1
// baseline (99.771 us; speedup 1.0000x reference)
//
#include <hip/hip_runtime.h>

#define DIM 512
#define BK 32

typedef unsigned int uint;
typedef unsigned short ushort;
typedef __attribute__((ext_vector_type(8))) short short8;
typedef __attribute__((ext_vector_type(4))) float f32x4;

// Pack two fp32 -> two bf16 (round-to-nearest via +0x8000, then byte-perm pack).
__device__ __forceinline__ uint pack_bf16(float a, float b) {
    union { float f; uint u; } ua, ub;
    ua.f = a; ub.f = b;
    uint x0 = ua.u + 0x8000u;
    uint x1 = ub.u + 0x8000u;
    return __builtin_amdgcn_perm(x1, x0, 0x07060302);
}

// ---- convert z (256x512 fp32) to bf16 ----
__global__ void zconv_kernel(const float* __restrict__ z, ushort* __restrict__ zb) {
    int t = blockIdx.x * 256 + threadIdx.x;   // 16384 threads * 8 elems = 131072
    int f = t * 8;
    float4 a = *(const float4*)(z + f);
    float4 b = *(const float4*)(z + f + 4);
    uint4 o;
    o.x = pack_bf16(a.x, a.y);
    o.y = pack_bf16(a.z, a.w);
    o.z = pack_bf16(b.x, b.y);
    o.w = pack_bf16(b.z, b.w);
    *(uint4*)(zb + f) = o;
}

// ---- exact fp32 diagonal T[a,a,a] ----
__global__ void diag_kernel(const float* __restrict__ x, const float* __restrict__ y,
                            const float* __restrict__ z, float* __restrict__ diag) {
    int a = blockIdx.x;
    int l = threadIdx.x;
    float s = 0.f;
    for (int d = l; d < DIM; d += 64)
        s += x[a * DIM + d] * y[a * DIM + d] * z[a * DIM + d];
    #pragma unroll
    for (int m = 1; m < 64; m <<= 1) s += __shfl_xor(s, m, 64);
    if (l == 0) diag[a] = s;
}

// ---- main batched GEMM + LSE-partial epilogue ----
// block = (a, rt): computes T[a, rt*128:(rt+1)*128, 0:256]
// 512 threads = 8 waves; wave (wr, wc) owns a 64x64 sub-tile as 4x4 MFMA tiles.
__global__ void gemm_kernel(const float* __restrict__ x, const float* __restrict__ y,
                            const ushort* __restrict__ zb,
                            float* __restrict__ rowM, float* __restrict__ rowS,
                            float* __restrict__ colM, float* __restrict__ colS) {
    __shared__ __align__(16) float xs[DIM];
    __shared__ __align__(16) ushort As[128 * BK];
    __shared__ __align__(16) ushort Bs[256 * BK];
    __shared__ float redA[128 * 4];
    __shared__ float rowMaxS[128];
    __shared__ float redB[256 * 2];
    __shared__ float colMaxS[256];

    const int tid = threadIdx.x;
    const int a   = blockIdx.x >> 1;
    const int rt  = blockIdx.x & 1;

    xs[tid] = x[a * DIM + tid];   // x[a,:] cached for the whole block

    const int lane = tid & 63;
    const int wave = tid >> 6;
    const int quad = lane >> 4;
    const int ln15 = lane & 15;
    const int wr = wave >> 2;     // 0..1  -> row offset wr*64
    const int wc = wave & 3;      // 0..3  -> col offset wc*64

    f32x4 acc[4][4];
    #pragma unroll
    for (int i = 0; i < 4; ++i)
        #pragma unroll
        for (int j = 0; j < 4; ++j)
            acc[i][j] = (f32x4){0.f, 0.f, 0.f, 0.f};

    const int fA = tid * 8;        // A staging: 4096 bf16 elems, 8 per thread
    const int rA = fA >> 5;        // 0..127
    const int kA = fA & 31;        // 0,8,16,24
    const float* yrow = y + (rt * 128 + rA) * DIM + kA;

    for (int kt = 0; kt < DIM / BK; ++kt) {
        const int k0 = kt * BK;
        __syncthreads();
        // stage A = bf16(x[a,k] * y[r,k])
        {
            float4 y0 = *(const float4*)(yrow + k0);
            float4 y1 = *(const float4*)(yrow + k0 + 4);
            float4 x0 = *(const float4*)(xs + k0 + kA);
            float4 x1 = *(const float4*)(xs + k0 + kA + 4);
            uint4 o;
            o.x = pack_bf16(y0.x * x0.x, y0.y * x0.y);
            o.y = pack_bf16(y0.z * x0.z, y0.w * x0.w);
            o.z = pack_bf16(y1.x * x1.x, y1.y * x1.y);
            o.w = pack_bf16(y1.z * x1.z, y1.w * x1.w);
            *(uint4*)(As + fA) = o;
        }
        // stage B = zb tile (256 rows x 32 k), 16 elems/thread
        #pragma unroll
        for (int h = 0; h < 2; ++h) {
            int f = h * 4096 + tid * 8;
            int s = f >> 5;
            int kk = f & 31;
            uint4 v = *(const uint4*)(zb + s * DIM + k0 + kk);
            *(uint4*)(Bs + f) = v;
        }
        __syncthreads();
        // fragments + MFMA
        short8 af[4], bfr[4];
        #pragma unroll
        for (int i = 0; i < 4; ++i)
            af[i] = *(const short8*)(As + (wr * 64 + i * 16 + ln15) * BK + quad * 8);
        #pragma unroll
        for (int j = 0; j < 4; ++j)
            bfr[j] = *(const short8*)(Bs + (wc * 64 + j * 16 + ln15) * BK + quad * 8);
        #pragma unroll
        for (int i = 0; i < 4; ++i)
            #pragma unroll
            for (int j = 0; j < 4; ++j)
                acc[i][j] = __builtin_amdgcn_mfma_f32_16x16x32_bf16(af[i], bfr[j], acc[i][j], 0, 0, 0);
    }
    __syncthreads();

    // ===== row-wise LSE partials (reduce over all 256 cols s) =====
    // lane owns rows r = wr*64 + i*16 + quad*4 + reg, cols n = wc*64 + j*16 + ln15
    #pragma unroll
    for (int i = 0; i < 4; ++i) {
        #pragma unroll
        for (int reg = 0; reg < 4; ++reg) {
            float m = fmaxf(fmaxf(acc[i][0][reg], acc[i][1][reg]),
                            fmaxf(acc[i][2][reg], acc[i][3][reg]));
            #pragma unroll
            for (int d = 1; d < 16; d <<= 1) m = fmaxf(m, __shfl_xor(m, d, 64));
            if (ln15 == 0) redA[(wr * 64 + i * 16 + quad * 4 + reg) * 4 + wc] = m;
        }
    }
    __syncthreads();
    if (tid < 128) {
        float m = fmaxf(fmaxf(redA[tid * 4 + 0], redA[tid * 4 + 1]),
                        fmaxf(redA[tid * 4 + 2], redA[tid * 4 + 3]));
        rowMaxS[tid] = m;
    }
    __syncthreads();
    #pragma unroll
    for (int i = 0; i < 4; ++i) {
        #pragma unroll
        for (int reg = 0; reg < 4; ++reg) {
            int r = wr * 64 + i * 16 + quad * 4 + reg;
            float rm = rowMaxS[r];
            float s = __expf(acc[i][0][reg] - rm) + __expf(acc[i][1][reg] - rm)
                    + __expf(acc[i][2][reg] - rm) + __expf(acc[i][3][reg] - rm);
            #pragma unroll
            for (int d = 1; d < 16; d <<= 1) s += __shfl_xor(s, d, 64);
            if (ln15 == 0) redA[r * 4 + wc] = s;
        }
    }
    __syncthreads();
    if (tid < 128) {
        float s = redA[tid * 4 + 0] + redA[tid * 4 + 1] + redA[tid * 4 + 2] + redA[tid * 4 + 3];
        int rg = rt * 128 + tid;
        rowM[a * 256 + rg] = rowMaxS[tid];
        rowS[a * 256 + rg] = s;
    }

    // ===== col-wise LSE partials (reduce over this block's 128 rows) =====
    #pragma unroll
    for (int j = 0; j < 4; ++j) {
        float m = -3.4e38f;
        #pragma unroll
        for (int i = 0; i < 4; ++i)
            #pragma unroll
            for (int reg = 0; reg < 4; ++reg)
                m = fmaxf(m, acc[i][j][reg]);
        m = fmaxf(m, __shfl_xor(m, 16, 64));
        m = fmaxf(m, __shfl_xor(m, 32, 64));
        if (quad == 0) redB[(wc * 64 + j * 16 + ln15) * 2 + wr] = m;
    }
    __syncthreads();
    if (tid < 256) colMaxS[tid] = fmaxf(redB[tid * 2], redB[tid * 2 + 1]);
    __syncthreads();
    #pragma unroll
    for (int j = 0; j < 4; ++j) {
        int n = wc * 64 + j * 16 + ln15;
        float cm = colMaxS[n];
        float s = 0.f;
        #pragma unroll
        for (int i = 0; i < 4; ++i)
            #pragma unroll
            for (int reg = 0; reg < 4; ++reg)
                s += __expf(acc[i][j][reg] - cm);
        s += __shfl_xor(s, 16, 64);
        s += __shfl_xor(s, 32, 64);
        if (quad == 0) redB[n * 2 + wr] = s;
    }
    __syncthreads();
    if (tid < 256) {
        float s = redB[tid * 2] + redB[tid * 2 + 1];
        colM[(a * 256 + tid) * 2 + rt] = colMaxS[tid];
        colS[(a * 256 + tid) * 2 + rt] = s;
    }
}

// ---- block-wide reductions over 256 threads ----
__device__ __forceinline__ float blk_max(float v, float* sm) {
    #pragma unroll
    for (int d = 1; d < 64; d <<= 1) v = fmaxf(v, __shfl_xor(v, d, 64));
    __syncthreads();
    if ((threadIdx.x & 63) == 0) sm[threadIdx.x >> 6] = v;
    __syncthreads();
    return fmaxf(fmaxf(sm[0], sm[1]), fmaxf(sm[2], sm[3]));
}
__device__ __forceinline__ float blk_sum(float v, float* sm) {
    #pragma unroll
    for (int d = 1; d < 64; d <<= 1) v += __shfl_xor(v, d, 64);
    __syncthreads();
    if ((threadIdx.x & 63) == 0) sm[threadIdx.x >> 6] = v;
    __syncthreads();
    return sm[0] + sm[1] + sm[2] + sm[3];
}

// ---- per-index LSE combine: M1[b], M2[b], M3[b] -> m123[b] ----
__global__ void combine_kernel(const float* __restrict__ rowM, const float* __restrict__ rowS,
                               const float* __restrict__ colM, const float* __restrict__ colS,
                               float* __restrict__ m123) {
    __shared__ float sm[4];
    int b = blockIdx.x, t = threadIdx.x;
    // M1[b] = LSE over r of (rowM[b,r], rowS[b,r])
    float m = rowM[b * 256 + t], s = rowS[b * 256 + t];
    float M = blk_max(m, sm);
    float S = blk_sum(s * __expf(m - M), sm);
    float M1 = M + __logf(S);
    // M2[b] = LSE over a of (rowM[a,b], rowS[a,b])
    m = rowM[t * 256 + b]; s = rowS[t * 256 + b];
    M = blk_max(m, sm);
    S = blk_sum(s * __expf(m - M), sm);
    float M2 = M + __logf(S);
    // M3[b] = LSE over (a, rt) of colM/colS[a, b, rt]
    float am = colM[(t * 256 + b) * 2 + 0], av = colS[(t * 256 + b) * 2 + 0];
    float bm = colM[(t * 256 + b) * 2 + 1], bv = colS[(t * 256 + b) * 2 + 1];
    m = fmaxf(am, bm);
    s = av * __expf(am - m) + bv * __expf(bm - m);
    M = blk_max(m, sm);
    S = blk_sum(s * __expf(m - M), sm);
    float M3 = M + __logf(S);
    if (t == 0) m123[b] = M1 + M2 + M3;
}

__global__ void final_kernel(const float* __restrict__ m123, const float* __restrict__ diag,
                             float* __restrict__ out) {
    __shared__ float sm[4];
    int t = threadIdx.x;
    float S1 = blk_sum(m123[t], sm);
    float S2 = blk_sum(diag[t], sm);
    if (t == 0) out[0] = S1 / 768.0f - S2 / 256.0f;
}

extern "C" void kernel_launch(void* const* d_in, const int* in_sizes, int n_in,
                              void* d_out, int out_size, void* d_ws, size_t ws_size,
                              hipStream_t stream) {
    const float* x = (const float*)d_in[0];
    const float* y = (const float*)d_in[1];
    const float* z = (const float*)d_in[2];
    char* w = (char*)d_ws;
    ushort* zb  = (ushort*)(w);                  // 262144 B
    float*  rowM = (float*)(w + 262144);         // 262144 B
    float*  rowS = (float*)(w + 524288);         // 262144 B
    float*  colM = (float*)(w + 786432);         // 524288 B
    float*  colS = (float*)(w + 1310720);        // 524288 B
    float*  diag = (float*)(w + 1835008);        // 1024 B
    float*  m123 = (float*)(w + 1836032);        // 1024 B
    float*  out  = (float*)d_out;

    zconv_kernel<<<64, 256, 0, stream>>>(z, zb);
    diag_kernel<<<256, 64, 0, stream>>>(x, y, z, diag);
    gemm_kernel<<<512, 512, 0, stream>>>(x, y, zb, rowM, rowS, colM, colS);
    combine_kernel<<<256, 256, 0, stream>>>(rowM, rowS, colM, colS, m123);
    final_kernel<<<1, 256, 0, stream>>>(m123, diag, out);
}